// Round 1
// baseline (202.761 us; speedup 1.0000x reference)
//
#include <hip/hip_runtime.h>
#include <hip/hip_bf16.h>
#include <cstdint>
#include <cstddef>

#define N_ROWS 8192
#define HDIM 512
#define INDIM 128
#define NHEADS 4
#define NNB 8

typedef __bf16 bf16_t;
typedef __bf16 bf16x8 __attribute__((ext_vector_type(8)));
typedef __bf16 bf16x4 __attribute__((ext_vector_type(4)));
typedef __bf16 bf16x2 __attribute__((ext_vector_type(2)));
typedef float f32x4 __attribute__((ext_vector_type(4)));

__device__ __forceinline__ float sigmoidf_(float x) { return 1.0f / (1.0f + expf(-x)); }

__device__ __forceinline__ void load_lds16(const void* g, void* l) {
  __builtin_amdgcn_global_load_lds(
      (const __attribute__((address_space(1))) void*)g,
      (__attribute__((address_space(3))) void*)l, 16, 0, 0);
}

// ---------------------------------------------------------------------------
// Pack: W1 = bf16([w_fg; w_ig]) (1024 x 2048), W2 = bf16([w_ih | w_hh]) (2048 x 640),
// A2[:, 0:128] = bf16(x)
// ---------------------------------------------------------------------------
__global__ __launch_bounds__(256) void pack_kernel(
    const float* __restrict__ w_fg, const float* __restrict__ w_ig,
    const float* __restrict__ w_ih, const float* __restrict__ w_hh,
    const float* __restrict__ x,
    bf16_t* __restrict__ W1, bf16_t* __restrict__ W2, bf16_t* __restrict__ A2)
{
  int idx = blockIdx.x * 256 + threadIdx.x;
  if (idx < 1024 * 2048) {
    int r = idx >> 11, k = idx & 2047;
    float v = (r < 512) ? w_fg[(size_t)r * 2048 + k] : w_ig[(size_t)(r - 512) * 2048 + k];
    W1[idx] = (bf16_t)v;
    return;
  }
  idx -= 1024 * 2048;
  if (idx < 2048 * 640) {
    int r = idx / 640, k = idx - r * 640;
    float v = (k < 128) ? w_ih[(size_t)r * 128 + k] : w_hh[(size_t)r * 512 + (k - 128)];
    W2[idx] = (bf16_t)v;
    return;
  }
  idx -= 2048 * 640;
  if (idx < N_ROWS * INDIM) {
    int n = idx >> 7, cc = idx & 127;
    A2[(size_t)n * 640 + cc] = (bf16_t)x[idx];
  }
}

// ---------------------------------------------------------------------------
// Attention + aggregation: per-row softmax over 8 neighbors, agg -> bf16
// ---------------------------------------------------------------------------
__global__ __launch_bounds__(256) void attn_agg_kernel(
    const float* __restrict__ h, const float* __restrict__ hs,
    const float* __restrict__ a_src, bf16_t* __restrict__ agg)
{
  __shared__ float s_hs[NNB][HDIM];   // 16 KB
  __shared__ float s_h[HDIM];         // 2 KB
  __shared__ float s_logit[NNB][NHEADS];
  __shared__ float s_self[NHEADS];

  const int n = blockIdx.x;
  const int t = threadIdx.x;
  const float* hs_n = hs + (size_t)n * (NNB * HDIM);
  const float* h_n  = h  + (size_t)n * HDIM;

  {
    const float4* s4 = (const float4*)hs_n;
    float4* d4 = (float4*)&s_hs[0][0];
#pragma unroll
    for (int i = 0; i < 4; ++i) d4[t + i * 256] = s4[t + i * 256];
    if (t < HDIM / 4) ((float4*)s_h)[t] = ((const float4*)h_n)[t];
  }
  __syncthreads();

  const int wave = t >> 6, lane = t & 63;
  // neighbor logits: each wave does 2 k's
#pragma unroll
  for (int kk = 0; kk < 2; ++kk) {
    const int k = wave * 2 + kk;
    float acc0 = 0.f, acc1 = 0.f, acc2 = 0.f, acc3 = 0.f;
#pragma unroll
    for (int i = 0; i < HDIM / 64; ++i) {
      const int hh = i * 64 + lane;
      const float v = s_hs[k][hh];
      const float4 av = *(const float4*)(a_src + (size_t)(HDIM + hh) * NHEADS);
      acc0 += v * av.x; acc1 += v * av.y; acc2 += v * av.z; acc3 += v * av.w;
    }
    float accs[NHEADS] = {acc0, acc1, acc2, acc3};
#pragma unroll
    for (int m = 0; m < NHEADS; ++m) {
      float a = accs[m];
#pragma unroll
      for (int off = 32; off > 0; off >>= 1) a += __shfl_xor(a, off);
      if (lane == 0) s_logit[k][m] = a;
    }
  }
  if (wave == 0) {  // self logits
    float acc0 = 0.f, acc1 = 0.f, acc2 = 0.f, acc3 = 0.f;
#pragma unroll
    for (int i = 0; i < HDIM / 64; ++i) {
      const int hh = i * 64 + lane;
      const float v = s_h[hh];
      const float4 av = *(const float4*)(a_src + (size_t)hh * NHEADS);
      acc0 += v * av.x; acc1 += v * av.y; acc2 += v * av.z; acc3 += v * av.w;
    }
    float accs[NHEADS] = {acc0, acc1, acc2, acc3};
#pragma unroll
    for (int m = 0; m < NHEADS; ++m) {
      float a = accs[m];
#pragma unroll
      for (int off = 32; off > 0; off >>= 1) a += __shfl_xor(a, off);
      if (lane == 0) s_self[m] = a;
    }
  }
  __syncthreads();

  // softmax weights (redundantly in every thread; trivial cost)
  float w[NNB][NHEADS];
#pragma unroll
  for (int m = 0; m < NHEADS; ++m) {
    const float sm = s_self[m];
    float mx = -1e30f;
#pragma unroll
    for (int k = 0; k < NNB; ++k) {
      float l = sm + s_logit[k][m];
      l = (l >= 0.f) ? l : 0.2f * l;
      w[k][m] = l;
      mx = fmaxf(mx, l);
    }
    float sum = 0.f;
#pragma unroll
    for (int k = 0; k < NNB; ++k) { const float e = expf(w[k][m] - mx); w[k][m] = e; sum += e; }
    const float inv = 1.f / sum;
#pragma unroll
    for (int k = 0; k < NNB; ++k) w[k][m] *= inv;
  }

  // agg[n, m*H + hh] = sum_k w[k][m] * hs[k][hh]; each thread does 2 adjacent hh
  bf16_t* agg_n = agg + (size_t)n * (NHEADS * HDIM);
  const int hh = t * 2;
  float e0[NNB], e1[NNB];
#pragma unroll
  for (int k = 0; k < NNB; ++k) { e0[k] = s_hs[k][hh]; e1[k] = s_hs[k][hh + 1]; }
#pragma unroll
  for (int m = 0; m < NHEADS; ++m) {
    float a0 = 0.f, a1 = 0.f;
#pragma unroll
    for (int k = 0; k < NNB; ++k) { a0 += w[k][m] * e0[k]; a1 += w[k][m] * e1[k]; }
    bf16x2 pk; pk[0] = (bf16_t)a0; pk[1] = (bf16_t)a1;
    *(bf16x2*)(agg_n + m * HDIM + hh) = pk;
  }
}

// ---------------------------------------------------------------------------
// m97-style bf16 GEMM, 128x128 tile, BK=32, 4 waves each 64x64.
// C[row,col] = sum_k A[row,k] * Bt[col,k]   (Bt = B^T, row-major N x K)
// EPI 1: spatial gates epilogue.  EPI 2: LSTM gate pre-activations -> bf16.
// ---------------------------------------------------------------------------
template <int EPI>
__global__ __launch_bounds__(256) void gemm_kernel(
    const bf16_t* __restrict__ A, int lda,
    const bf16_t* __restrict__ Bt, int ldb, int K,
    const float* __restrict__ p0, const float* __restrict__ p1,
    const float* __restrict__ p2, const float* __restrict__ p3,
    float* __restrict__ q0, bf16_t* __restrict__ q1)
{
  __shared__ bf16_t At[128][32];
  __shared__ bf16_t Bs[128][32];

  const int tid  = threadIdx.x;
  const int wave = tid >> 6, lane = tid & 63;
  const int wr = wave >> 1, wc = wave & 1;
  const int bm0 = blockIdx.x * 128;
  const int bn0 = blockIdx.y * 128;

  f32x4 acc[4][4] = {};

  const int srow = tid >> 2;            // 0..63
  const int scol = (tid & 3) * 8;       // bf16 elems (16B chunks)
  const bf16_t* Ag0 = A  + (size_t)(bm0 + srow)      * lda + scol;
  const bf16_t* Ag1 = A  + (size_t)(bm0 + srow + 64) * lda + scol;
  const bf16_t* Bg0 = Bt + (size_t)(bn0 + srow)      * ldb + scol;
  const bf16_t* Bg1 = Bt + (size_t)(bn0 + srow + 64) * ldb + scol;
  bf16_t* lA0 = &At[srow][scol];
  bf16_t* lA1 = &At[srow + 64][scol];
  bf16_t* lB0 = &Bs[srow][scol];
  bf16_t* lB1 = &Bs[srow + 64][scol];

  const int frow = lane & 15;
  const int kk = (lane >> 4) * 8;

  for (int k0 = 0; k0 < K; k0 += 32) {
    load_lds16(Ag0 + k0, lA0);
    load_lds16(Ag1 + k0, lA1);
    load_lds16(Bg0 + k0, lB0);
    load_lds16(Bg1 + k0, lB1);
    __syncthreads();

    bf16x8 af[4], bf[4];
#pragma unroll
    for (int i = 0; i < 4; ++i) af[i] = *(const bf16x8*)&At[wr * 64 + i * 16 + frow][kk];
#pragma unroll
    for (int j = 0; j < 4; ++j) bf[j] = *(const bf16x8*)&Bs[wc * 64 + j * 16 + frow][kk];
#pragma unroll
    for (int i = 0; i < 4; ++i)
#pragma unroll
      for (int j = 0; j < 4; ++j)
        acc[i][j] = __builtin_amdgcn_mfma_f32_16x16x32_bf16(af[i], bf[j], acc[i][j], 0, 0, 0);
    __syncthreads();
  }

  // epilogue
  const int col_in = lane & 15;
  const int row_in = (lane >> 4) * 4;
#pragma unroll
  for (int i = 0; i < 4; ++i) {
#pragma unroll
    for (int j = 0; j < 4; ++j) {
      const int col = bn0 + wc * 64 + j * 16 + col_in;
#pragma unroll
      for (int r = 0; r < 4; ++r) {
        const int row = bm0 + wr * 64 + i * 16 + row_in + r;
        const float v = acc[i][j][r];
        if (EPI == 1) {
          // cols 0..511: forget-gate -> cprime (fp32); cols 512..1023: input-gate -> A2 bf16
          if (col < 512) {
            const float s = sigmoidf_(v + p0[col]);
            q0[(size_t)row * 512 + col] = p2[(size_t)row * 512 + col] * s;
          } else {
            const int jj = col - 512;
            const float s = sigmoidf_(v + p1[jj]);
            q1[(size_t)row * 640 + 128 + jj] = (bf16_t)(p3[(size_t)row * 512 + jj] * s);
          }
        } else {
          // LSTM gate pre-activation
          q1[(size_t)row * 2048 + col] = (bf16_t)(v + p0[col] + p1[col]);
        }
      }
    }
  }
}

// ---------------------------------------------------------------------------
// Final elementwise: activations + c_new/h_new
// ---------------------------------------------------------------------------
__global__ __launch_bounds__(256) void final_kernel(
    const bf16_t* __restrict__ gates, const float* __restrict__ cprime,
    float* __restrict__ out)
{
  const int idx = blockIdx.x * 256 + threadIdx.x;  // one float4 of H per thread
  const int n = idx >> 7;
  const int q = (idx & 127) * 4;
  const bf16_t* g = gates + (size_t)n * 2048;
  const bf16x4 gi = *(const bf16x4*)(g + q);
  const bf16x4 gf = *(const bf16x4*)(g + 512 + q);
  const bf16x4 gg = *(const bf16x4*)(g + 1024 + q);
  const bf16x4 go = *(const bf16x4*)(g + 1536 + q);
  const float4 cp = *(const float4*)(cprime + (size_t)n * 512 + q);
  const float cpv[4] = {cp.x, cp.y, cp.z, cp.w};
  float hn[4], cn[4];
#pragma unroll
  for (int r = 0; r < 4; ++r) {
    const float i_g = sigmoidf_((float)gi[r]);
    const float f_g = sigmoidf_((float)gf[r]);
    const float g_g = tanhf((float)gg[r]);
    const float o_g = sigmoidf_((float)go[r]);
    const float c = f_g * cpv[r] + i_g * g_g;
    cn[r] = c;
    hn[r] = o_g * tanhf(c);
  }
  *(float4*)(out + (size_t)n * 512 + q) = *(float4*)hn;
  *(float4*)(out + (size_t)(N_ROWS * HDIM) + (size_t)n * 512 + q) = *(float4*)cn;
}

// ---------------------------------------------------------------------------
extern "C" void kernel_launch(void* const* d_in, const int* in_sizes, int n_in,
                              void* d_out, int out_size, void* d_ws, size_t ws_size,
                              hipStream_t stream) {
  const float* x     = (const float*)d_in[0];
  const float* h     = (const float*)d_in[1];
  const float* c     = (const float*)d_in[2];
  const float* hsp   = (const float*)d_in[3];
  const float* a_src = (const float*)d_in[4];
  const float* w_fg  = (const float*)d_in[5];
  const float* b_fg  = (const float*)d_in[6];
  const float* w_ig  = (const float*)d_in[7];
  const float* b_ig  = (const float*)d_in[8];
  const float* w_ih  = (const float*)d_in[9];
  const float* w_hh  = (const float*)d_in[10];
  const float* b_ih  = (const float*)d_in[11];
  const float* b_hh  = (const float*)d_in[12];
  float* out = (float*)d_out;

  uint8_t* ws = (uint8_t*)d_ws;
  bf16_t* agg    = (bf16_t*)(ws);                 // 8192*2048*2 = 33,554,432
  bf16_t* W1     = (bf16_t*)(ws + 33554432);      // 1024*2048*2 =  4,194,304
  bf16_t* W2     = (bf16_t*)(ws + 37748736);      // 2048*640*2  =  2,621,440
  bf16_t* A2     = (bf16_t*)(ws + 40370176);      // 8192*640*2  = 10,485,760
  float*  cprime = (float*) (ws + 50855936);      // 8192*512*4  = 16,777,216
  bf16_t* gates  = (bf16_t*)(ws + 67633152);      // 8192*2048*2 = 33,554,432
  // total 101,187,584 bytes

  pack_kernel<<<17408, 256, 0, stream>>>(w_fg, w_ig, w_ih, w_hh, x, W1, W2, A2);
  attn_agg_kernel<<<N_ROWS, 256, 0, stream>>>(h, hsp, a_src, agg);
  gemm_kernel<1><<<dim3(64, 8), 256, 0, stream>>>(
      agg, 2048, W1, 2048, 2048, b_fg, b_ig, c, h, cprime, A2);
  gemm_kernel<2><<<dim3(64, 16), 256, 0, stream>>>(
      A2, 640, W2, 640, 640, b_ih, b_hh, nullptr, nullptr, nullptr, gates);
  final_kernel<<<4096, 256, 0, stream>>>(gates, cprime, out);
}